// Round 13
// baseline (1521.032 us; speedup 1.0000x reference)
//
#include <hip/hip_runtime.h>
#include <hip/hip_bf16.h>

#define NB 16
#define NN 2048
#define KNNK 16
#define MM 1024
#define RC1 (NB*NN*KNNK)
#define RC2 (NB*MM*KNNK)

typedef unsigned long long u64;
typedef __attribute__((ext_vector_type(8))) short short8;
typedef __attribute__((ext_vector_type(4))) float f32x4;

__device__ __forceinline__ float frn_mul(float a, float b){ return __fmul_rn(a,b); }
__device__ __forceinline__ float frn_add(float a, float b){ return __fadd_rn(a,b); }
__device__ __forceinline__ float frn_sub(float a, float b){ return __fsub_rn(a,b); }
__device__ __forceinline__ float silu_f(float x){ return x / (1.0f + __expf(-x)); }
__device__ __forceinline__ u64 umax64(u64 a, u64 b){ return a > b ? a : b; }

__device__ __forceinline__ unsigned f32_sortable(float f){
  unsigned u = __float_as_uint(f);
  return u ^ ((unsigned)((int)u >> 31) | 0x80000000u);
}
__device__ __forceinline__ unsigned short f2bf(float f){
  unsigned u = __float_as_uint(f);
  return (unsigned short)((u + 0x7FFFu + ((u >> 16) & 1u)) >> 16);
}
__device__ __forceinline__ float bf2f(unsigned short h){
  return __uint_as_float(((unsigned)h) << 16);
}

__device__ __forceinline__ void atomicMaxF(unsigned* addr, float v){
  if (v >= 0.f) atomicMax((int*)addr, (int)__float_as_uint(v));
  else          atomicMin(addr, __float_as_uint(v));
}
__device__ __forceinline__ void atomicMinF(unsigned* addr, float v){
  if (v >= 0.f) atomicMin((int*)addr, (int)__float_as_uint(v));
  else          atomicMax(addr, __float_as_uint(v));
}

__global__ __launch_bounds__(256) void init_kernel(float* stats1, float* stats2a, float* stats2b,
                                                   unsigned* gmax, unsigned* gmin, unsigned* sync){
  int t = blockIdx.x*256 + threadIdx.x;
  if (t < 128) stats1[t] = 0.f;
  if (t < 256) stats2a[t] = 0.f;
  if (t < 512) stats2b[t] = 0.f;
  if (t < 4096){ gmax[t] = 0xFF800000u; gmin[t] = 0x7F800000u; }
  if (t >= 4096 && t < 4160) sync[t - 4096] = 0u;
}

template<int CNT>
__device__ __forceinline__ void knn_scan(const float4* pts, int jbase,
                                         float xi, float yi, float zi, float n2i, u64* best){
#pragma unroll
  for (int p = 0; p < KNNK; ++p) best[p] = ~0ull;
  for (int jj = 0; jj < CNT; ++jj){
    float4 v = pts[jbase + jj];
    float e = frn_add(frn_add(frn_mul(xi,v.x), frn_mul(yi,v.y)), frn_mul(zi,v.z));
    float d = frn_sub(frn_add(n2i, v.w), frn_mul(2.0f, e));
    u64 key = ((u64)f32_sortable(d) << 32) | (unsigned)(jbase + jj);
    if (key < best[KNNK-1]){
      u64 cur = key;
#pragma unroll
      for (int p = 0; p < KNNK; ++p){
        u64 mn = best[p] < cur ? best[p] : cur;
        u64 mx = best[p] < cur ? cur : best[p];
        best[p] = mn; cur = mx;
      }
    }
  }
}

// ---- K0 mega-pipeline via device flags:
//   blocks 0..15     FPS           -> sets sync[1+b]
//   blocks 16..271   knn1+merge+c1stats -> increments sync[0]
//   blocks 272..1295 conv1 apply   -> spins sync[0]==256
//   blocks 1296..1551 knn2         -> spins sync[1+b]
__global__ __launch_bounds__(256) void k0_mega(const float* __restrict__ pos,
    int* __restrict__ idxf, float* __restrict__ pos2, int* __restrict__ idx1,
    int* __restrict__ idx2, const float* __restrict__ W1, const float* __restrict__ b1,
    const float* __restrict__ g1, const float* __restrict__ be1,
    float* __restrict__ stats1, unsigned short* __restrict__ hbf, unsigned* sync){
  __shared__ __align__(16) char smem[82*1024];
  int tid = threadIdx.x;
  if (blockIdx.x < 16){
    // ---------------- FPS ----------------
    int b = blockIdx.x;
    float4* pts4 = (float4*)smem;
    int* sel = (int*)(smem + 32*1024);
    u64* wred = (u64*)(smem + 36*1024);
    const float* pb = pos + (size_t)b*NN*3;
    float X[8], Y[8], Z[8], MD[8];
    unsigned LO[8];
#pragma unroll
    for (int q = 0; q < 8; ++q){
      int p = tid + 256*q;
      float x = pb[p*3+0], y = pb[p*3+1], z = pb[p*3+2];
      X[q] = x; Y[q] = y; Z[q] = z;
      LO[q] = ~(unsigned)p;
      pts4[p] = make_float4(x, y, z, 0.f);
    }
    float qx = pb[0], qy = pb[1], qz = pb[2];
#pragma unroll
    for (int q = 0; q < 8; ++q){
      float dx = frn_sub(X[q],qx), dy = frn_sub(Y[q],qy), dz = frn_sub(Z[q],qz);
      MD[q] = frn_add(frn_add(frn_mul(dx,dx), frn_mul(dy,dy)), frn_mul(dz,dz));
    }
    if (tid == 0) sel[0] = 0;
    int wv = tid >> 6;
    __syncthreads();
    for (int s = 1; s < MM; ++s){
      u64 t0 = umax64(((u64)__float_as_uint(MD[0])<<32)|LO[0], ((u64)__float_as_uint(MD[1])<<32)|LO[1]);
      u64 t1 = umax64(((u64)__float_as_uint(MD[2])<<32)|LO[2], ((u64)__float_as_uint(MD[3])<<32)|LO[3]);
      u64 t2 = umax64(((u64)__float_as_uint(MD[4])<<32)|LO[4], ((u64)__float_as_uint(MD[5])<<32)|LO[5]);
      u64 t3 = umax64(((u64)__float_as_uint(MD[6])<<32)|LO[6], ((u64)__float_as_uint(MD[7])<<32)|LO[7]);
      u64 kk = umax64(umax64(t0, t1), umax64(t2, t3));
#define RED_DPP(CTRL) { \
      unsigned lo_ = (unsigned)kk, hi_ = (unsigned)(kk>>32); \
      unsigned plo = (unsigned)__builtin_amdgcn_update_dpp((int)lo_,(int)lo_,CTRL,0xF,0xF,false); \
      unsigned phi = (unsigned)__builtin_amdgcn_update_dpp((int)hi_,(int)hi_,CTRL,0xF,0xF,false); \
      u64 o = ((u64)phi<<32)|plo; kk = o > kk ? o : kk; }
      RED_DPP(0xB1)
      RED_DPP(0x4E)
      RED_DPP(0x124)
      RED_DPP(0x128)
      RED_DPP(0x142)
      RED_DPP(0x143)
#undef RED_DPP
      int par = s & 1;
      if ((tid & 63) == 63) wred[par*4 + wv] = kk;
      __syncthreads();
      const u64* wr = wred + par*4;
      u64 K = umax64(umax64(wr[0], wr[1]), umax64(wr[2], wr[3]));
      unsigned wp = ~(unsigned)K;
      if (tid == 0) sel[s] = (int)wp;
      float4 wc = pts4[wp];
#pragma unroll
      for (int q = 0; q < 8; ++q){
        float dx = frn_sub(X[q],wc.x), dy = frn_sub(Y[q],wc.y), dz = frn_sub(Z[q],wc.z);
        float d = frn_add(frn_add(frn_mul(dx,dx), frn_mul(dy,dy)), frn_mul(dz,dz));
        MD[q] = fminf(MD[q], d);
      }
    }
    __syncthreads();
    for (int m = tid; m < MM; m += 256){
      int j = sel[m];
      idxf[b*MM + m] = j;
      float4 c = pts4[j];
      pos2[(size_t)(b*MM+m)*3+0] = c.x;
      pos2[(size_t)(b*MM+m)*3+1] = c.y;
      pos2[(size_t)(b*MM+m)*3+2] = c.z;
    }
    __syncthreads();
    __threadfence();
    if (tid == 0) atomicExch(&sync[1 + b], 1u);
  } else if (blockIdx.x < 272){
    // ---------------- knn1 chunk scan + merge + conv1 stats ----------------
    int cid = blockIdx.x - 16;
    int b = cid >> 4;
    int rb16 = cid & 15;
    float4* pts4 = (float4*)smem;
    u64* cres = (u64*)(smem + 32*1024);              // 256*17*8 = 34816
    int* idxl = (int*)(smem + 32*1024 + 34816);      // 128*17*4 = 8704
    float* red = (float*)(smem + 32*1024 + 34816 + 8704);
    const float* pb = pos + (size_t)b*NN*3;
    for (int i = tid; i < NN; i += 256){
      float x = pb[i*3+0], y = pb[i*3+1], z = pb[i*3+2];
      float n2 = frn_add(frn_add(frn_mul(x,x), frn_mul(y,y)), frn_mul(z,z));
      pts4[i] = make_float4(x, y, z, n2);
    }
    __syncthreads();
    int lrow = tid & 127;
    int ch = tid >> 7;
    int i = rb16*128 + lrow;
    float4 qv = pts4[i];
    u64 best[KNNK];
    knn_scan<1024>(pts4, ch*1024, qv.x, qv.y, qv.z, qv.w, best);
#pragma unroll
    for (int p = 0; p < KNNK; ++p) cres[tid*17 + p] = best[p];
    __syncthreads();
    if (tid < 128){
      const u64* A = cres + tid*17;
      const u64* B = cres + (tid + 128)*17;
      int ia = 0, ib = 0;
      int* op = idx1 + ((size_t)(b*NN + rb16*128 + tid))*KNNK;
#pragma unroll
      for (int p = 0; p < KNNK; ++p){
        u64 ka = A[ia], kb = B[ib];
        int v;
        if (ka < kb){ v = (int)(unsigned)ka; ++ia; }
        else        { v = (int)(unsigned)kb; ++ib; }
        op[p] = v;
        idxl[tid*17 + p] = v;
      }
    }
    __syncthreads();
    int lane = tid & 63, wv = tid >> 6;
    float w[6];
#pragma unroll
    for (int f = 0; f < 6; ++f) w[f] = W1[f*64 + lane];
    float bias = b1[lane];
    float ssum = 0.f, ssq = 0.f;
    for (int r = 0; r < 32; ++r){
      int lr = wv*32 + r;
      float4 pi = pts4[rb16*128 + lr];
      const int* ip = idxl + lr*17;
#pragma unroll 4
      for (int k = 0; k < KNNK; ++k){
        int j = ip[k];
        float4 pj = pts4[j];
        float y = bias;
        y = fmaf(pj.x, w[0], y); y = fmaf(pj.y, w[1], y); y = fmaf(pj.z, w[2], y);
        y = fmaf(pj.x - pi.x, w[3], y); y = fmaf(pj.y - pi.y, w[4], y); y = fmaf(pj.z - pi.z, w[5], y);
        ssum += y; ssq = fmaf(y, y, ssq);
      }
    }
    red[(wv*64+lane)*2+0] = ssum; red[(wv*64+lane)*2+1] = ssq;
    __syncthreads();
    if (tid < 64){
      float s = red[(0*64+lane)*2]+red[(1*64+lane)*2]+red[(2*64+lane)*2]+red[(3*64+lane)*2];
      float q = red[(0*64+lane)*2+1]+red[(1*64+lane)*2+1]+red[(2*64+lane)*2+1]+red[(3*64+lane)*2+1];
      atomicAdd(&stats1[lane], s);
      atomicAdd(&stats1[64+lane], q);
    }
    __syncthreads();
    __threadfence();
    if (tid == 0) atomicAdd(&sync[0], 1u);
  } else if (blockIdx.x < 1296){
    // ---------------- conv1 apply (spin until all 256 stats blocks done) ----------------
    if (tid == 0){
      while (atomicAdd(&sync[0], 0u) < 256u) __builtin_amdgcn_s_sleep(32);
    }
    __syncthreads();
    __threadfence();
    int lane = tid & 63, wv = tid >> 6;
    int wave = (blockIdx.x - 272)*4 + wv;
    float w[6];
#pragma unroll
    for (int f = 0; f < 6; ++f) w[f] = W1[f*64 + lane];
    float bias = b1[lane];
    const float inv = 1.0f / (float)RC1;
    float mu = stats1[lane] * inv;
    float var = fmaxf(stats1[64+lane]*inv - mu*mu, 0.f);
    float sc = rsqrtf(var + 1e-5f) * g1[lane];
    float sh = be1[lane] - mu*sc;
    for (int r = 0; r < 8; ++r){
      int row = wave*8 + r;
      int b = row >> 11, ii = row & 2047;
      const float* pi = pos + ((size_t)(b*NN + ii))*3;
      float xi = pi[0], yi = pi[1], zi = pi[2];
      const int* ip = idx1 + (size_t)row * KNNK;
      float ymn = INFINITY, ymx = -INFINITY;
#pragma unroll 4
      for (int k = 0; k < KNNK; ++k){
        int j = ip[k];
        const float* pj = pos + ((size_t)(b*NN + j))*3;
        float xj = pj[0], yj = pj[1], zj = pj[2];
        float y = bias;
        y = fmaf(xj, w[0], y); y = fmaf(yj, w[1], y); y = fmaf(zj, w[2], y);
        y = fmaf(xj - xi, w[3], y); y = fmaf(yj - yi, w[4], y); y = fmaf(zj - zi, w[5], y);
        ymn = fminf(ymn, y); ymx = fmaxf(ymx, y);
      }
      hbf[((size_t)row << 6) + lane] = f2bf(fmaxf(silu_f(fmaf(ymx, sc, sh)), silu_f(fmaf(ymn, sc, sh))));
    }
  } else {
    // ---------------- knn2 (spin until its batch's FPS done) ----------------
    int cid = blockIdx.x - 1296;         // 0..255
    int b = cid >> 4;
    int rb = cid & 15;
    if (tid == 0){
      while (atomicAdd(&sync[1 + b], 0u) == 0u) __builtin_amdgcn_s_sleep(32);
    }
    __syncthreads();
    __threadfence();
    float4* sm = (float4*)smem;          // 16 KB
    u64* cres = (u64*)(smem + 16*1024);  // 32 KB
    const float* pb = pos2 + (size_t)b*MM*3;
    for (int t = tid; t < MM; t += 256){
      float x = pb[t*3+0], y = pb[t*3+1], z = pb[t*3+2];
      float n2 = frn_add(frn_add(frn_mul(x,x), frn_mul(y,y)), frn_mul(z,z));
      sm[t] = make_float4(x, y, z, n2);
    }
    __syncthreads();
    int trow = tid & 63, ch = tid >> 6;
    int i = rb*64 + trow;
    float4 qv = sm[i];
    u64 best[KNNK];
    knn_scan<256>(sm, ch*256, qv.x, qv.y, qv.z, qv.w, best);
#pragma unroll
    for (int p = 0; p < KNNK; ++p) cres[tid*KNNK + p] = best[p];
    __syncthreads();
    if (tid < 64){
      const u64* L0 = cres + tid*KNNK;
      const u64* L1 = cres + (64 + tid)*KNNK;
      const u64* L2 = cres + (128 + tid)*KNNK;
      const u64* L3 = cres + (192 + tid)*KNNK;
      int o0=0, o1=0, o2=0, o3=0;
      int* op = idx2 + ((size_t)(b*MM + rb*64 + tid))*KNNK;
#pragma unroll
      for (int p = 0; p < KNNK; ++p){
        u64 k0 = L0[o0], k1 = L1[o1], k2 = L2[o2], k3 = L3[o3];
        u64 m01 = k0 < k1 ? k0 : k1;
        u64 m23 = k2 < k3 ? k2 : k3;
        u64 m = m01 < m23 ? m01 : m23;
        op[p] = (int)(unsigned)m;
        o0 += (m == k0); o1 += (m == k1); o2 += (m == k2); o3 += (m == k3);
      }
    }
  }
}

// ---- conv2a: MFMA 16x16x32 bf16 (r12 verbatim) ----
__global__ __launch_bounds__(256) void conv2a_kernel(
    const unsigned short* __restrict__ hbf, const int* __restrict__ idxf,
    const float* __restrict__ pos2, const int* __restrict__ idx2,
    const float* __restrict__ W2a, const float* __restrict__ b2a,
    float* __restrict__ stats2a, __hip_bfloat16* __restrict__ y2a){
  __shared__ __align__(16) unsigned short At[64*104];
  __shared__ __align__(16) unsigned short Wt[128*104];
  __shared__ int qs[64];
  int tid = threadIdx.x;
  int lane = tid & 63, wvi = tid >> 6;
  for (int i = tid; i < 96*128; i += 256){
    int k = i >> 7, c = i & 127;
    Wt[c*104 + k] = (k < 67) ? f2bf(W2a[k*128 + c]) : (unsigned short)0;
  }
  for (int i = tid; i < 64*104/2; i += 256) ((unsigned*)At)[i] = 0u;
  __syncthreads();
  int cb = wvi*32;
  short8 bfrag[2][3];
#pragma unroll
  for (int cf = 0; cf < 2; ++cf)
#pragma unroll
    for (int kf = 0; kf < 3; ++kf){
      int col = cb + cf*16 + (lane & 15);
      bfrag[cf][kf] = *(short8*)(Wt + col*104 + kf*32 + (lane>>4)*8);
    }
  float bb[2] = { b2a[cb + (lane & 15)], b2a[cb + 16 + (lane & 15)] };
  float ssum[2] = {0.f, 0.f}, ssq[2] = {0.f, 0.f};
  for (int t = 0; t < 4; ++t){
    int tbase = (blockIdx.x*4 + t)*64;
    if (t > 0) __syncthreads();
    if (tid < 64){
      int grow = tbase + tid;
      int b = grow >> 14;
      int m = (grow >> 4) & 1023;
      int j = idx2[grow];
      int q = idxf[b*MM + j];
      qs[tid] = b*NN + q;
      const float* pm = pos2 + ((size_t)(b*MM + m))*3;
      const float* pj = pos2 + ((size_t)(b*MM + j))*3;
      At[tid*104 + 64] = f2bf(pj[0]-pm[0]);
      At[tid*104 + 65] = f2bf(pj[1]-pm[1]);
      At[tid*104 + 66] = f2bf(pj[2]-pm[2]);
    }
    __syncthreads();
    {
      int r = tid & 63, ck = tid >> 6;
      const unsigned short* src = hbf + (size_t)qs[r]*64 + ck*16;
      short8 v0 = *(const short8*)(src);
      short8 v1 = *(const short8*)(src + 8);
      *(short8*)(At + r*104 + ck*16) = v0;
      *(short8*)(At + r*104 + ck*16 + 8) = v1;
    }
    __syncthreads();
#pragma unroll
    for (int rf = 0; rf < 4; ++rf){
      int r = rf*16 + (lane & 15);
      short8 af[3];
#pragma unroll
      for (int kf = 0; kf < 3; ++kf)
        af[kf] = *(short8*)(At + r*104 + kf*32 + (lane>>4)*8);
#pragma unroll
      for (int cf = 0; cf < 2; ++cf){
        f32x4 acc = {0.f,0.f,0.f,0.f};
#pragma unroll
        for (int kf = 0; kf < 3; ++kf)
          acc = __builtin_amdgcn_mfma_f32_16x16x32_bf16(af[kf], bfrag[cf][kf], acc, 0, 0, 0);
#pragma unroll
        for (int jj = 0; jj < 4; ++jj){
          int row = tbase + rf*16 + (lane>>4)*4 + jj;
          int col = cb + cf*16 + (lane & 15);
          float y = acc[jj] + bb[cf];
          ssum[cf] += y; ssq[cf] = fmaf(y, y, ssq[cf]);
          y2a[(size_t)row*128 + col] = __float2bfloat16(y);
        }
      }
    }
  }
#pragma unroll
  for (int cf = 0; cf < 2; ++cf){
#pragma unroll
    for (int off = 16; off <= 32; off += 16){
      ssum[cf] += __shfl_xor(ssum[cf], off);
      ssq[cf]  += __shfl_xor(ssq[cf],  off);
    }
  }
  if ((lane >> 4) == 0){
    atomicAdd(&stats2a[cb + lane], ssum[0]);
    atomicAdd(&stats2a[128 + cb + lane], ssq[0]);
    atomicAdd(&stats2a[cb + 16 + lane], ssum[1]);
    atomicAdd(&stats2a[128 + cb + 16 + lane], ssq[1]);
  }
}

// ---- conv2b: MFMA 16x16x32 bf16 (r7 verbatim) ----
__global__ __launch_bounds__(256) void conv2b_kernel(
    const __hip_bfloat16* __restrict__ y2a, const float* __restrict__ stats2a,
    const float* __restrict__ g2a, const float* __restrict__ be2a,
    const float* __restrict__ W2b, const float* __restrict__ b2b,
    float* __restrict__ stats2b, unsigned* __restrict__ gmax, unsigned* __restrict__ gmin){
  __shared__ __align__(16) char Albs[64*256];
  __shared__ __align__(16) char Btbs[64*256];
  __shared__ float sc2a[128], sh2a[128];
  int tid = threadIdx.x;
  int lane = tid & 63, wvi = tid >> 6;
  int ct = blockIdx.x & 3;
  int rb = blockIdx.x >> 2;
  int c0 = ct * 64;
  int batch = rb >> 5;
  if (tid < 128){
    const float inv = 1.0f / (float)RC2;
    float mu = stats2a[tid] * inv;
    float var = fmaxf(stats2a[128+tid]*inv - mu*mu, 0.f);
    float s = rsqrtf(var + 1e-5f) * g2a[tid];
    sc2a[tid] = s; sh2a[tid] = be2a[tid] - mu*s;
  }
  {
    int cc = tid & 63, u0 = tid >> 6;
#pragma unroll
    for (int i = 0; i < 4; ++i){
      int u = u0 + i*4;
      unsigned short hb[8];
#pragma unroll
      for (int e = 0; e < 8; ++e) hb[e] = f2bf(W2b[(size_t)(u*8+e)*256 + c0 + cc]);
      *(short8*)(Btbs + cc*256 + u*16) = *(short8*)hb;
    }
  }
  __syncthreads();
  short8 bfrag[4];
#pragma unroll
  for (int kb4 = 0; kb4 < 4; ++kb4){
    int col_local = wvi*16 + (lane & 15);
    bfrag[kb4] = *(short8*)(Btbs + col_local*256 + kb4*64 + (lane>>4)*16);
  }
  float bb = b2b[c0 + wvi*16 + (lane & 15)];
  float vmn = INFINITY, vmx = -INFINITY, ssum = 0.f, ssq = 0.f;
  const unsigned short* y2u = (const unsigned short*)y2a;
  int sr = tid & 63, su = tid >> 6;
  for (int tile = 0; tile < 8; ++tile){
    int row0 = rb*512 + tile*64;
    if (tile > 0) __syncthreads();
#pragma unroll
    for (int i = 0; i < 4; ++i){
      int u = su + i*4;
      short8 v = *(const short8*)(y2u + (size_t)(row0 + sr)*128 + u*8);
      unsigned short ha[8];
#pragma unroll
      for (int e = 0; e < 8; ++e){
        int k = u*8 + e;
        float f = bf2f((unsigned short)v[e]);
        ha[e] = f2bf(silu_f(fmaf(f, sc2a[k], sh2a[k])));
      }
      *(short8*)(Albs + sr*256 + ((u*16) ^ ((sr & 7) << 4))) = *(short8*)ha;
    }
    __syncthreads();
#pragma unroll
    for (int sl = 0; sl < 4; ++sl){
      f32x4 acc = {0.f, 0.f, 0.f, 0.f};
#pragma unroll
      for (int kb4 = 0; kb4 < 4; ++kb4){
        int r = sl*16 + (lane & 15);
        short8 afrag = *(short8*)(Albs + r*256 + ((kb4*64 + (lane>>4)*16) ^ ((r & 7) << 4)));
        acc = __builtin_amdgcn_mfma_f32_16x16x32_bf16(afrag, bfrag[kb4], acc, 0, 0, 0);
      }
#pragma unroll
      for (int j = 0; j < 4; ++j){
        float y = acc[j] + bb;
        vmn = fminf(vmn, y); vmx = fmaxf(vmx, y);
        ssum += y; ssq = fmaf(y, y, ssq);
      }
    }
  }
#pragma unroll
  for (int off = 16; off <= 32; off += 16){
    vmn  = fminf(vmn,  __shfl_xor(vmn,  off));
    vmx  = fmaxf(vmx,  __shfl_xor(vmx,  off));
    ssum = ssum + __shfl_xor(ssum, off);
    ssq  = ssq  + __shfl_xor(ssq,  off);
  }
  if ((lane >> 4) == 0){
    int c = c0 + wvi*16 + lane;
    atomicAdd(&stats2b[c], ssum);
    atomicAdd(&stats2b[256+c], ssq);
    atomicMaxF(&gmax[batch*256 + c], vmx);
    atomicMinF(&gmin[batch*256 + c], vmn);
  }
}

__global__ __launch_bounds__(256) void final_kernel(
    const float* __restrict__ stats2b, const unsigned* __restrict__ gmax,
    const unsigned* __restrict__ gmin, const float* __restrict__ g2b,
    const float* __restrict__ be2b, float* __restrict__ out){
  int t = blockIdx.x*256 + threadIdx.x;
  if (t >= NB*256) return;
  int c = t & 255;
  const float inv = 1.0f / (float)RC2;
  float mu = stats2b[c]*inv;
  float var = fmaxf(stats2b[256+c]*inv - mu*mu, 0.f);
  float sc = rsqrtf(var + 1e-5f)*g2b[c];
  float sh = be2b[c] - mu*sc;
  float mx = __uint_as_float(gmax[t]);
  float mn = __uint_as_float(gmin[t]);
  out[t] = fmaxf(silu_f(fmaf(mx, sc, sh)), silu_f(fmaf(mn, sc, sh)));
}

extern "C" void kernel_launch(void* const* d_in, const int* in_sizes, int n_in,
                              void* d_out, int out_size, void* d_ws, size_t ws_size,
                              hipStream_t stream){
  (void)in_sizes; (void)n_in; (void)out_size; (void)ws_size;
  const float* pos  = (const float*)d_in[0];
  const float* W1   = (const float*)d_in[1];
  const float* b1   = (const float*)d_in[2];
  const float* g1   = (const float*)d_in[3];
  const float* be1  = (const float*)d_in[4];
  const float* W2a  = (const float*)d_in[5];
  const float* b2a  = (const float*)d_in[6];
  const float* g2a  = (const float*)d_in[7];
  const float* be2a = (const float*)d_in[8];
  const float* W2b  = (const float*)d_in[9];
  const float* b2b  = (const float*)d_in[10];
  const float* g2b  = (const float*)d_in[11];
  const float* be2b = (const float*)d_in[12];

  char* w = (char*)d_ws;
  size_t off = 0;
  auto carve = [&](size_t bytes)->void*{ void* p = w + off; off += (bytes + 255) & ~(size_t)255; return p; };
  int*      idx1    = (int*)carve((size_t)NB*NN*KNNK*4);
  unsigned short* hbf = (unsigned short*)carve((size_t)NB*NN*64*2);
  int*      idxf    = (int*)carve((size_t)NB*MM*4);
  float*    pos2    = (float*)carve((size_t)NB*MM*3*4);
  int*      idx2    = (int*)carve((size_t)NB*MM*KNNK*4);
  float*    stats1  = (float*)carve(128*4);
  float*    stats2a = (float*)carve(256*4);
  float*    stats2b = (float*)carve(512*4);
  unsigned* gmax    = (unsigned*)carve(4096*4);
  unsigned* gmin    = (unsigned*)carve(4096*4);
  unsigned* sync    = (unsigned*)carve(64*4);
  __hip_bfloat16* y2a = (__hip_bfloat16*)carve((size_t)RC2*128*2);

  init_kernel<<<dim3(17), dim3(256), 0, stream>>>(stats1, stats2a, stats2b, gmax, gmin, sync);
  k0_mega<<<dim3(1552), dim3(256), 0, stream>>>(pos, idxf, pos2, idx1, idx2,
                                                W1, b1, g1, be1, stats1, hbf, sync);
  conv2a_kernel<<<dim3(1024), dim3(256), 0, stream>>>(hbf, idxf, pos2, idx2, W2a, b2a, stats2a, y2a);
  conv2b_kernel<<<dim3(2048), dim3(256), 0, stream>>>(y2a, stats2a, g2a, be2a, W2b, b2b, stats2b, gmax, gmin);
  final_kernel<<<dim3(16), dim3(256), 0, stream>>>(stats2b, gmax, gmin, g2b, be2b, (float*)d_out);
}

// Round 14
// 800.299 us; speedup vs baseline: 1.9006x; 1.9006x over previous
//
#include <hip/hip_runtime.h>
#include <hip/hip_bf16.h>

#define NB 16
#define NN 2048
#define KNNK 16
#define MM 1024
#define RC1 (NB*NN*KNNK)
#define RC2 (NB*MM*KNNK)

typedef unsigned long long u64;
typedef __attribute__((ext_vector_type(8))) short short8;
typedef __attribute__((ext_vector_type(4))) float f32x4;

__device__ __forceinline__ float frn_mul(float a, float b){ return __fmul_rn(a,b); }
__device__ __forceinline__ float frn_add(float a, float b){ return __fadd_rn(a,b); }
__device__ __forceinline__ float frn_sub(float a, float b){ return __fsub_rn(a,b); }
__device__ __forceinline__ float silu_f(float x){ return x / (1.0f + __expf(-x)); }
__device__ __forceinline__ u64 umax64(u64 a, u64 b){ return a > b ? a : b; }

__device__ __forceinline__ unsigned f32_sortable(float f){
  unsigned u = __float_as_uint(f);
  return u ^ ((unsigned)((int)u >> 31) | 0x80000000u);
}
__device__ __forceinline__ unsigned short f2bf(float f){
  unsigned u = __float_as_uint(f);
  return (unsigned short)((u + 0x7FFFu + ((u >> 16) & 1u)) >> 16);
}
__device__ __forceinline__ float bf2f(unsigned short h){
  return __uint_as_float(((unsigned)h) << 16);
}

__device__ __forceinline__ void atomicMaxF(unsigned* addr, float v){
  if (v >= 0.f) atomicMax((int*)addr, (int)__float_as_uint(v));
  else          atomicMin(addr, __float_as_uint(v));
}
__device__ __forceinline__ void atomicMinF(unsigned* addr, float v){
  if (v >= 0.f) atomicMin((int*)addr, (int)__float_as_uint(v));
  else          atomicMax(addr, __float_as_uint(v));
}

__global__ __launch_bounds__(256) void init_kernel(float* stats1, float* stats2a, float* stats2b,
                                                   unsigned* gmax, unsigned* gmin){
  int t = blockIdx.x*256 + threadIdx.x;
  if (t < 128) stats1[t] = 0.f;
  if (t < 256) stats2a[t] = 0.f;
  if (t < 512) stats2b[t] = 0.f;
  if (t < 4096){ gmax[t] = 0xFF800000u; gmin[t] = 0x7F800000u; }
}

template<int CNT>
__device__ __forceinline__ void knn_scan(const float4* pts, int jbase,
                                         float xi, float yi, float zi, float n2i, u64* best){
#pragma unroll
  for (int p = 0; p < KNNK; ++p) best[p] = ~0ull;
  for (int jj = 0; jj < CNT; ++jj){
    float4 v = pts[jbase + jj];
    float e = frn_add(frn_add(frn_mul(xi,v.x), frn_mul(yi,v.y)), frn_mul(zi,v.z));
    float d = frn_sub(frn_add(n2i, v.w), frn_mul(2.0f, e));
    u64 key = ((u64)f32_sortable(d) << 32) | (unsigned)(jbase + jj);
    if (key < best[KNNK-1]){
      u64 cur = key;
#pragma unroll
      for (int p = 0; p < KNNK; ++p){
        u64 mn = best[p] < cur ? best[p] : cur;
        u64 mx = best[p] < cur ? cur : best[p];
        best[p] = mn; cur = mx;
      }
    }
  }
}

// ---- K0: blocks 0..15 = FPS; blocks 16..271 = knn1 chunk scan + merge + c1stats (r12 verbatim) ----
__global__ __launch_bounds__(256) void k0_fps_knn1(const float* __restrict__ pos,
    int* __restrict__ idxf, float* __restrict__ pos2, int* __restrict__ idx1,
    const float* __restrict__ W1, const float* __restrict__ b1, float* __restrict__ stats1){
  __shared__ __align__(16) char smem[77*1024];
  int tid = threadIdx.x;
  if (blockIdx.x < 16){
    int b = blockIdx.x;
    float4* pts4 = (float4*)smem;
    int* sel = (int*)(smem + 32*1024);
    u64* wred = (u64*)(smem + 36*1024);
    const float* pb = pos + (size_t)b*NN*3;
    float X[8], Y[8], Z[8], MD[8];
    unsigned LO[8];
#pragma unroll
    for (int q = 0; q < 8; ++q){
      int p = tid + 256*q;
      float x = pb[p*3+0], y = pb[p*3+1], z = pb[p*3+2];
      X[q] = x; Y[q] = y; Z[q] = z;
      LO[q] = ~(unsigned)p;
      pts4[p] = make_float4(x, y, z, 0.f);
    }
    float qx = pb[0], qy = pb[1], qz = pb[2];
#pragma unroll
    for (int q = 0; q < 8; ++q){
      float dx = frn_sub(X[q],qx), dy = frn_sub(Y[q],qy), dz = frn_sub(Z[q],qz);
      MD[q] = frn_add(frn_add(frn_mul(dx,dx), frn_mul(dy,dy)), frn_mul(dz,dz));
    }
    if (tid == 0) sel[0] = 0;
    int wv = tid >> 6;
    __syncthreads();
    for (int s = 1; s < MM; ++s){
      u64 t0 = umax64(((u64)__float_as_uint(MD[0])<<32)|LO[0], ((u64)__float_as_uint(MD[1])<<32)|LO[1]);
      u64 t1 = umax64(((u64)__float_as_uint(MD[2])<<32)|LO[2], ((u64)__float_as_uint(MD[3])<<32)|LO[3]);
      u64 t2 = umax64(((u64)__float_as_uint(MD[4])<<32)|LO[4], ((u64)__float_as_uint(MD[5])<<32)|LO[5]);
      u64 t3 = umax64(((u64)__float_as_uint(MD[6])<<32)|LO[6], ((u64)__float_as_uint(MD[7])<<32)|LO[7]);
      u64 kk = umax64(umax64(t0, t1), umax64(t2, t3));
#define RED_DPP(CTRL) { \
      unsigned lo_ = (unsigned)kk, hi_ = (unsigned)(kk>>32); \
      unsigned plo = (unsigned)__builtin_amdgcn_update_dpp((int)lo_,(int)lo_,CTRL,0xF,0xF,false); \
      unsigned phi = (unsigned)__builtin_amdgcn_update_dpp((int)hi_,(int)hi_,CTRL,0xF,0xF,false); \
      u64 o = ((u64)phi<<32)|plo; kk = o > kk ? o : kk; }
      RED_DPP(0xB1)
      RED_DPP(0x4E)
      RED_DPP(0x124)
      RED_DPP(0x128)
      RED_DPP(0x142)
      RED_DPP(0x143)
#undef RED_DPP
      int par = s & 1;
      if ((tid & 63) == 63) wred[par*4 + wv] = kk;
      __syncthreads();
      const u64* wr = wred + par*4;
      u64 K = umax64(umax64(wr[0], wr[1]), umax64(wr[2], wr[3]));
      unsigned wp = ~(unsigned)K;
      if (tid == 0) sel[s] = (int)wp;
      float4 wc = pts4[wp];
#pragma unroll
      for (int q = 0; q < 8; ++q){
        float dx = frn_sub(X[q],wc.x), dy = frn_sub(Y[q],wc.y), dz = frn_sub(Z[q],wc.z);
        float d = frn_add(frn_add(frn_mul(dx,dx), frn_mul(dy,dy)), frn_mul(dz,dz));
        MD[q] = fminf(MD[q], d);
      }
    }
    __syncthreads();
    for (int m = tid; m < MM; m += 256){
      int j = sel[m];
      idxf[b*MM + m] = j;
      float4 c = pts4[j];
      pos2[(size_t)(b*MM+m)*3+0] = c.x;
      pos2[(size_t)(b*MM+m)*3+1] = c.y;
      pos2[(size_t)(b*MM+m)*3+2] = c.z;
    }
  } else {
    int cid = blockIdx.x - 16;
    int b = cid >> 4;
    int rb16 = cid & 15;
    float4* pts4 = (float4*)smem;
    u64* cres = (u64*)(smem + 32*1024);
    int* idxl = (int*)(smem + 32*1024 + 34816);
    float* red = (float*)(smem + 32*1024 + 34816 + 8704);
    const float* pb = pos + (size_t)b*NN*3;
    for (int i = tid; i < NN; i += 256){
      float x = pb[i*3+0], y = pb[i*3+1], z = pb[i*3+2];
      float n2 = frn_add(frn_add(frn_mul(x,x), frn_mul(y,y)), frn_mul(z,z));
      pts4[i] = make_float4(x, y, z, n2);
    }
    __syncthreads();
    int lrow = tid & 127;
    int ch = tid >> 7;
    int i = rb16*128 + lrow;
    float4 qv = pts4[i];
    u64 best[KNNK];
    knn_scan<1024>(pts4, ch*1024, qv.x, qv.y, qv.z, qv.w, best);
#pragma unroll
    for (int p = 0; p < KNNK; ++p) cres[tid*17 + p] = best[p];
    __syncthreads();
    if (tid < 128){
      const u64* A = cres + tid*17;
      const u64* B = cres + (tid + 128)*17;
      int ia = 0, ib = 0;
      int* op = idx1 + ((size_t)(b*NN + rb16*128 + tid))*KNNK;
#pragma unroll
      for (int p = 0; p < KNNK; ++p){
        u64 ka = A[ia], kb = B[ib];
        int v;
        if (ka < kb){ v = (int)(unsigned)ka; ++ia; }
        else        { v = (int)(unsigned)kb; ++ib; }
        op[p] = v;
        idxl[tid*17 + p] = v;
      }
    }
    __syncthreads();
    int lane = tid & 63, wv = tid >> 6;
    float w[6];
#pragma unroll
    for (int f = 0; f < 6; ++f) w[f] = W1[f*64 + lane];
    float bias = b1[lane];
    float ssum = 0.f, ssq = 0.f;
    for (int r = 0; r < 32; ++r){
      int lr = wv*32 + r;
      float4 pi = pts4[rb16*128 + lr];
      const int* ip = idxl + lr*17;
#pragma unroll 4
      for (int k = 0; k < KNNK; ++k){
        int j = ip[k];
        float4 pj = pts4[j];
        float y = bias;
        y = fmaf(pj.x, w[0], y); y = fmaf(pj.y, w[1], y); y = fmaf(pj.z, w[2], y);
        y = fmaf(pj.x - pi.x, w[3], y); y = fmaf(pj.y - pi.y, w[4], y); y = fmaf(pj.z - pi.z, w[5], y);
        ssum += y; ssq = fmaf(y, y, ssq);
      }
    }
    red[(wv*64+lane)*2+0] = ssum; red[(wv*64+lane)*2+1] = ssq;
    __syncthreads();
    if (tid < 64){
      float s = red[(0*64+lane)*2]+red[(1*64+lane)*2]+red[(2*64+lane)*2]+red[(3*64+lane)*2];
      float q = red[(0*64+lane)*2+1]+red[(1*64+lane)*2+1]+red[(2*64+lane)*2+1]+red[(3*64+lane)*2+1];
      atomicAdd(&stats1[lane], s);
      atomicAdd(&stats1[64+lane], q);
    }
  }
}

// ---- K1: blocks 0..255 = knn2; blocks 256..1279 = conv1 apply (batch pos staged in LDS) ----
__global__ __launch_bounds__(256) void k1_knn2_c1apply(
    const float* __restrict__ pos2, int* __restrict__ idx2,
    const float* __restrict__ pos, const int* __restrict__ idx1,
    const float* __restrict__ W1, const float* __restrict__ b1,
    const float* __restrict__ g1, const float* __restrict__ be1,
    const float* __restrict__ stats1, unsigned short* __restrict__ hbf){
  __shared__ __align__(16) char smem[48*1024];
  int tid = threadIdx.x;
  if (blockIdx.x < 256){
    int b = blockIdx.x >> 4;
    int rb = blockIdx.x & 15;
    float4* sm = (float4*)smem;
    u64* cres = (u64*)(smem + 16*1024);
    const float* pb = pos2 + (size_t)b*MM*3;
    for (int t = tid; t < MM; t += 256){
      float x = pb[t*3+0], y = pb[t*3+1], z = pb[t*3+2];
      float n2 = frn_add(frn_add(frn_mul(x,x), frn_mul(y,y)), frn_mul(z,z));
      sm[t] = make_float4(x, y, z, n2);
    }
    __syncthreads();
    int trow = tid & 63, ch = tid >> 6;
    int i = rb*64 + trow;
    float4 qv = sm[i];
    u64 best[KNNK];
    knn_scan<256>(sm, ch*256, qv.x, qv.y, qv.z, qv.w, best);
#pragma unroll
    for (int p = 0; p < KNNK; ++p) cres[tid*KNNK + p] = best[p];
    __syncthreads();
    if (tid < 64){
      const u64* L0 = cres + tid*KNNK;
      const u64* L1 = cres + (64 + tid)*KNNK;
      const u64* L2 = cres + (128 + tid)*KNNK;
      const u64* L3 = cres + (192 + tid)*KNNK;
      int o0=0, o1=0, o2=0, o3=0;
      int* op = idx2 + ((size_t)(b*MM + rb*64 + tid))*KNNK;
#pragma unroll
      for (int p = 0; p < KNNK; ++p){
        u64 k0 = L0[o0], k1 = L1[o1], k2 = L2[o2], k3 = L3[o3];
        u64 m01 = k0 < k1 ? k0 : k1;
        u64 m23 = k2 < k3 ? k2 : k3;
        u64 m = m01 < m23 ? m01 : m23;
        op[p] = (int)(unsigned)m;
        o0 += (m == k0); o1 += (m == k1); o2 += (m == k2); o3 += (m == k3);
      }
    }
  } else {
    // conv1 apply: block covers 32 consecutive rows of ONE batch; stage that batch's pos
    float4* pts4 = (float4*)smem;        // 2048 * 16B = 32 KB
    int bblk = blockIdx.x - 256;         // 0..1023
    int b = bblk >> 6;                   // 64 blocks per batch
    const float* pb = pos + (size_t)b*NN*3;
    for (int i = tid; i < NN; i += 256)
      pts4[i] = make_float4(pb[i*3+0], pb[i*3+1], pb[i*3+2], 0.f);
    __syncthreads();
    int lane = tid & 63, wv = tid >> 6;
    int wave = bblk*4 + wv;
    float w[6];
#pragma unroll
    for (int f = 0; f < 6; ++f) w[f] = W1[f*64 + lane];
    float bias = b1[lane];
    const float inv = 1.0f / (float)RC1;
    float mu = stats1[lane] * inv;
    float var = fmaxf(stats1[64+lane]*inv - mu*mu, 0.f);
    float sc = rsqrtf(var + 1e-5f) * g1[lane];
    float sh = be1[lane] - mu*sc;
    for (int r = 0; r < 8; ++r){
      int row = wave*8 + r;
      int ii = row & 2047;
      float4 pi = pts4[ii];
      const int* ip = idx1 + (size_t)row * KNNK;
      float ymn = INFINITY, ymx = -INFINITY;
#pragma unroll 4
      for (int k = 0; k < KNNK; ++k){
        int j = ip[k];
        float4 pj = pts4[j];
        float y = bias;
        y = fmaf(pj.x, w[0], y); y = fmaf(pj.y, w[1], y); y = fmaf(pj.z, w[2], y);
        y = fmaf(pj.x - pi.x, w[3], y); y = fmaf(pj.y - pi.y, w[4], y); y = fmaf(pj.z - pi.z, w[5], y);
        ymn = fminf(ymn, y); ymx = fmaxf(ymx, y);
      }
      hbf[((size_t)row << 6) + lane] = f2bf(fmaxf(silu_f(fmaf(ymx, sc, sh)), silu_f(fmaf(ymn, sc, sh))));
    }
  }
}

// ---- conv2a: MFMA 16x16x32 bf16 (r12 verbatim) ----
__global__ __launch_bounds__(256) void conv2a_kernel(
    const unsigned short* __restrict__ hbf, const int* __restrict__ idxf,
    const float* __restrict__ pos2, const int* __restrict__ idx2,
    const float* __restrict__ W2a, const float* __restrict__ b2a,
    float* __restrict__ stats2a, __hip_bfloat16* __restrict__ y2a){
  __shared__ __align__(16) unsigned short At[64*104];
  __shared__ __align__(16) unsigned short Wt[128*104];
  __shared__ int qs[64];
  int tid = threadIdx.x;
  int lane = tid & 63, wvi = tid >> 6;
  for (int i = tid; i < 96*128; i += 256){
    int k = i >> 7, c = i & 127;
    Wt[c*104 + k] = (k < 67) ? f2bf(W2a[k*128 + c]) : (unsigned short)0;
  }
  for (int i = tid; i < 64*104/2; i += 256) ((unsigned*)At)[i] = 0u;
  __syncthreads();
  int cb = wvi*32;
  short8 bfrag[2][3];
#pragma unroll
  for (int cf = 0; cf < 2; ++cf)
#pragma unroll
    for (int kf = 0; kf < 3; ++kf){
      int col = cb + cf*16 + (lane & 15);
      bfrag[cf][kf] = *(short8*)(Wt + col*104 + kf*32 + (lane>>4)*8);
    }
  float bb[2] = { b2a[cb + (lane & 15)], b2a[cb + 16 + (lane & 15)] };
  float ssum[2] = {0.f, 0.f}, ssq[2] = {0.f, 0.f};
  for (int t = 0; t < 4; ++t){
    int tbase = (blockIdx.x*4 + t)*64;
    if (t > 0) __syncthreads();
    if (tid < 64){
      int grow = tbase + tid;
      int b = grow >> 14;
      int m = (grow >> 4) & 1023;
      int j = idx2[grow];
      int q = idxf[b*MM + j];
      qs[tid] = b*NN + q;
      const float* pm = pos2 + ((size_t)(b*MM + m))*3;
      const float* pj = pos2 + ((size_t)(b*MM + j))*3;
      At[tid*104 + 64] = f2bf(pj[0]-pm[0]);
      At[tid*104 + 65] = f2bf(pj[1]-pm[1]);
      At[tid*104 + 66] = f2bf(pj[2]-pm[2]);
    }
    __syncthreads();
    {
      int r = tid & 63, ck = tid >> 6;
      const unsigned short* src = hbf + (size_t)qs[r]*64 + ck*16;
      short8 v0 = *(const short8*)(src);
      short8 v1 = *(const short8*)(src + 8);
      *(short8*)(At + r*104 + ck*16) = v0;
      *(short8*)(At + r*104 + ck*16 + 8) = v1;
    }
    __syncthreads();
#pragma unroll
    for (int rf = 0; rf < 4; ++rf){
      int r = rf*16 + (lane & 15);
      short8 af[3];
#pragma unroll
      for (int kf = 0; kf < 3; ++kf)
        af[kf] = *(short8*)(At + r*104 + kf*32 + (lane>>4)*8);
#pragma unroll
      for (int cf = 0; cf < 2; ++cf){
        f32x4 acc = {0.f,0.f,0.f,0.f};
#pragma unroll
        for (int kf = 0; kf < 3; ++kf)
          acc = __builtin_amdgcn_mfma_f32_16x16x32_bf16(af[kf], bfrag[cf][kf], acc, 0, 0, 0);
#pragma unroll
        for (int jj = 0; jj < 4; ++jj){
          int row = tbase + rf*16 + (lane>>4)*4 + jj;
          int col = cb + cf*16 + (lane & 15);
          float y = acc[jj] + bb[cf];
          ssum[cf] += y; ssq[cf] = fmaf(y, y, ssq[cf]);
          y2a[(size_t)row*128 + col] = __float2bfloat16(y);
        }
      }
    }
  }
#pragma unroll
  for (int cf = 0; cf < 2; ++cf){
#pragma unroll
    for (int off = 16; off <= 32; off += 16){
      ssum[cf] += __shfl_xor(ssum[cf], off);
      ssq[cf]  += __shfl_xor(ssq[cf],  off);
    }
  }
  if ((lane >> 4) == 0){
    atomicAdd(&stats2a[cb + lane], ssum[0]);
    atomicAdd(&stats2a[128 + cb + lane], ssq[0]);
    atomicAdd(&stats2a[cb + 16 + lane], ssum[1]);
    atomicAdd(&stats2a[128 + cb + 16 + lane], ssq[1]);
  }
}

// ---- conv2b: MFMA, 128 cols/block (halves redundant A staging+SiLU), 1024 blocks ----
__global__ __launch_bounds__(256) void conv2b_kernel(
    const __hip_bfloat16* __restrict__ y2a, const float* __restrict__ stats2a,
    const float* __restrict__ g2a, const float* __restrict__ be2a,
    const float* __restrict__ W2b, const float* __restrict__ b2b,
    float* __restrict__ stats2b, unsigned* __restrict__ gmax, unsigned* __restrict__ gmin){
  __shared__ __align__(16) char Albs[64*256];    // 16 KB
  __shared__ __align__(16) char Btbs[128*256];   // 32 KB
  __shared__ float sc2a[128], sh2a[128];
  int tid = threadIdx.x;
  int lane = tid & 63, wvi = tid >> 6;
  int ct = blockIdx.x & 1;
  int rb = blockIdx.x >> 1;                      // 0..511, 512 rows each
  int c0 = ct * 128;
  int batch = rb >> 5;
  if (tid < 128){
    const float inv = 1.0f / (float)RC2;
    float mu = stats2a[tid] * inv;
    float var = fmaxf(stats2a[128+tid]*inv - mu*mu, 0.f);
    float s = rsqrtf(var + 1e-5f) * g2a[tid];
    sc2a[tid] = s; sh2a[tid] = be2a[tid] - mu*s;
  }
  {
    int cc = tid & 127, u0 = tid >> 7;           // 128 cols, 2 u-groups
#pragma unroll
    for (int i = 0; i < 8; ++i){
      int u = u0 + i*2;                          // 0..15
      unsigned short hb[8];
#pragma unroll
      for (int e = 0; e < 8; ++e) hb[e] = f2bf(W2b[(size_t)(u*8+e)*256 + c0 + cc]);
      *(short8*)(Btbs + cc*256 + u*16) = *(short8*)hb;
    }
  }
  __syncthreads();
  short8 bfrag[2][4];
#pragma unroll
  for (int cf = 0; cf < 2; ++cf)
#pragma unroll
    for (int kb4 = 0; kb4 < 4; ++kb4){
      int col_local = wvi*32 + cf*16 + (lane & 15);
      bfrag[cf][kb4] = *(short8*)(Btbs + col_local*256 + kb4*64 + (lane>>4)*16);
    }
  float bb[2] = { b2b[c0 + wvi*32 + (lane & 15)], b2b[c0 + wvi*32 + 16 + (lane & 15)] };
  float vmn[2] = {INFINITY, INFINITY}, vmx[2] = {-INFINITY, -INFINITY};
  float ssum[2] = {0.f, 0.f}, ssq[2] = {0.f, 0.f};
  const unsigned short* y2u = (const unsigned short*)y2a;
  int sr = tid & 63, su = tid >> 6;
  for (int tile = 0; tile < 8; ++tile){
    int row0 = rb*512 + tile*64;
    if (tile > 0) __syncthreads();
#pragma unroll
    for (int i = 0; i < 4; ++i){
      int u = su + i*4;
      short8 v = *(const short8*)(y2u + (size_t)(row0 + sr)*128 + u*8);
      unsigned short ha[8];
#pragma unroll
      for (int e = 0; e < 8; ++e){
        int k = u*8 + e;
        float f = bf2f((unsigned short)v[e]);
        ha[e] = f2bf(silu_f(fmaf(f, sc2a[k], sh2a[k])));
      }
      *(short8*)(Albs + sr*256 + ((u*16) ^ ((sr & 7) << 4))) = *(short8*)ha;
    }
    __syncthreads();
#pragma unroll
    for (int sl = 0; sl < 4; ++sl){
      int r = sl*16 + (lane & 15);
      short8 af[4];
#pragma unroll
      for (int kb4 = 0; kb4 < 4; ++kb4)
        af[kb4] = *(short8*)(Albs + r*256 + ((kb4*64 + (lane>>4)*16) ^ ((r & 7) << 4)));
#pragma unroll
      for (int cf = 0; cf < 2; ++cf){
        f32x4 acc = {0.f, 0.f, 0.f, 0.f};
#pragma unroll
        for (int kb4 = 0; kb4 < 4; ++kb4)
          acc = __builtin_amdgcn_mfma_f32_16x16x32_bf16(af[kb4], bfrag[cf][kb4], acc, 0, 0, 0);
#pragma unroll
        for (int j = 0; j < 4; ++j){
          float y = acc[j] + bb[cf];
          vmn[cf] = fminf(vmn[cf], y); vmx[cf] = fmaxf(vmx[cf], y);
          ssum[cf] += y; ssq[cf] = fmaf(y, y, ssq[cf]);
        }
      }
    }
  }
#pragma unroll
  for (int cf = 0; cf < 2; ++cf){
#pragma unroll
    for (int off = 16; off <= 32; off += 16){
      vmn[cf]  = fminf(vmn[cf],  __shfl_xor(vmn[cf],  off));
      vmx[cf]  = fmaxf(vmx[cf],  __shfl_xor(vmx[cf],  off));
      ssum[cf] = ssum[cf] + __shfl_xor(ssum[cf], off);
      ssq[cf]  = ssq[cf]  + __shfl_xor(ssq[cf],  off);
    }
  }
  if ((lane >> 4) == 0){
#pragma unroll
    for (int cf = 0; cf < 2; ++cf){
      int c = c0 + wvi*32 + cf*16 + lane;
      atomicAdd(&stats2b[c], ssum[cf]);
      atomicAdd(&stats2b[256+c], ssq[cf]);
      atomicMaxF(&gmax[batch*256 + c], vmx[cf]);
      atomicMinF(&gmin[batch*256 + c], vmn[cf]);
    }
  }
}

__global__ __launch_bounds__(256) void final_kernel(
    const float* __restrict__ stats2b, const unsigned* __restrict__ gmax,
    const unsigned* __restrict__ gmin, const float* __restrict__ g2b,
    const float* __restrict__ be2b, float* __restrict__ out){
  int t = blockIdx.x*256 + threadIdx.x;
  if (t >= NB*256) return;
  int c = t & 255;
  const float inv = 1.0f / (float)RC2;
  float mu = stats2b[c]*inv;
  float var = fmaxf(stats2b[256+c]*inv - mu*mu, 0.f);
  float sc = rsqrtf(var + 1e-5f)*g2b[c];
  float sh = be2b[c] - mu*sc;
  float mx = __uint_as_float(gmax[t]);
  float mn = __uint_as_float(gmin[t]);
  out[t] = fmaxf(silu_f(fmaf(mx, sc, sh)), silu_f(fmaf(mn, sc, sh)));
}

extern "C" void kernel_launch(void* const* d_in, const int* in_sizes, int n_in,
                              void* d_out, int out_size, void* d_ws, size_t ws_size,
                              hipStream_t stream){
  (void)in_sizes; (void)n_in; (void)out_size; (void)ws_size;
  const float* pos  = (const float*)d_in[0];
  const float* W1   = (const float*)d_in[1];
  const float* b1   = (const float*)d_in[2];
  const float* g1   = (const float*)d_in[3];
  const float* be1  = (const float*)d_in[4];
  const float* W2a  = (const float*)d_in[5];
  const float* b2a  = (const float*)d_in[6];
  const float* g2a  = (const float*)d_in[7];
  const float* be2a = (const float*)d_in[8];
  const float* W2b  = (const float*)d_in[9];
  const float* b2b  = (const float*)d_in[10];
  const float* g2b  = (const float*)d_in[11];
  const float* be2b = (const float*)d_in[12];

  char* w = (char*)d_ws;
  size_t off = 0;
  auto carve = [&](size_t bytes)->void*{ void* p = w + off; off += (bytes + 255) & ~(size_t)255; return p; };
  int*      idx1    = (int*)carve((size_t)NB*NN*KNNK*4);
  unsigned short* hbf = (unsigned short*)carve((size_t)NB*NN*64*2);
  int*      idxf    = (int*)carve((size_t)NB*MM*4);
  float*    pos2    = (float*)carve((size_t)NB*MM*3*4);
  int*      idx2    = (int*)carve((size_t)NB*MM*KNNK*4);
  float*    stats1  = (float*)carve(128*4);
  float*    stats2a = (float*)carve(256*4);
  float*    stats2b = (float*)carve(512*4);
  unsigned* gmax    = (unsigned*)carve(4096*4);
  unsigned* gmin    = (unsigned*)carve(4096*4);
  __hip_bfloat16* y2a = (__hip_bfloat16*)carve((size_t)RC2*128*2);

  init_kernel<<<dim3(16), dim3(256), 0, stream>>>(stats1, stats2a, stats2b, gmax, gmin);
  k0_fps_knn1<<<dim3(272), dim3(256), 0, stream>>>(pos, idxf, pos2, idx1, W1, b1, stats1);
  k1_knn2_c1apply<<<dim3(1280), dim3(256), 0, stream>>>(pos2, idx2, pos, idx1, W1, b1, g1, be1, stats1, hbf);
  conv2a_kernel<<<dim3(1024), dim3(256), 0, stream>>>(hbf, idxf, pos2, idx2, W2a, b2a, stats2a, y2a);
  conv2b_kernel<<<dim3(1024), dim3(256), 0, stream>>>(y2a, stats2a, g2a, be2a, W2b, b2b, stats2b, gmax, gmin);
  final_kernel<<<dim3(16), dim3(256), 0, stream>>>(stats2b, gmax, gmin, g2b, be2b, (float*)d_out);
}